// Round 21
// baseline (76.387 us; speedup 1.0000x reference)
//
#include <hip/hip_runtime.h>

// 2-dispatch windowed NMS (bit-exact vs the JAX reference).
// R21: R20's two nulls falsified work-based theories; remaining lever is
// per-dispatch fixed cost (~3-4us launch+clock-ramp each). Merged scan into
// the mask kernel via last-block-done pattern (device-scope handshake,
// cross-XCD safe): mask parallelism preserved (112 blocks), one dispatch
// fewer. Winner-independent output -> deterministic.
//  K1 select448 : histogram + cnt_gt + bucket-list rank -> g_boxes/g_order;
//                 resets g_done. (R18-proven)
//  K2 maskscan_p: grid (chunk,batch); each block writes its chunk's mask
//                 rows; 7th finisher per batch runs the R19 wave-0 scan +
//                 block-wide insurance + output inline.
// Fallback single kernel (R1-proven) outside the fast path.

constexpr int   kN       = 2048;
constexpr int   kB       = 16;        // max batches in fast path
constexpr int   kM       = 448;       // sorted window (multiple of 64)
constexpr int   kNCH     = kM / 64;   // 7 chunks
constexpr int   kMW      = kM / 32;   // 14 mask words per row
constexpr int   kNB      = 8192;      // score buckets
constexpr int   kCandMax = 1024;
constexpr int   kT       = 1024;      // 16 waves
constexpr float kIouThr  = 0.7f;

__device__ __align__(16) float4   g_boxes[kB][kM];     // canonical, rank order
__device__            int         g_order[kB][kM];     // original idx by rank
__device__ __align__(16) unsigned g_mask[kB][kM][16];  // 64B rows (words 0..13)
__device__            int         g_done[kB];          // mask-block counters

__device__ __forceinline__ unsigned scoreKey(float s) {
    const unsigned b = __float_as_uint(s);
    if (s == 0.0f) return 0x80000000u;
    return (b & 0x80000000u) ? ~b : (b | 0x80000000u);
}

__device__ __forceinline__ float4 canonBox(const float4 bx) {
    const float cy1 = fminf(bx.x, bx.z), cy2 = fmaxf(bx.x, bx.z);
    const float cx1 = fminf(bx.y, bx.w), cx2 = fmaxf(bx.y, bx.w);
    return make_float4(cy1, cx1, cy2, cx2);
}

// ---------------------------------------------------------------- K1: select
__global__ __launch_bounds__(kT, 1)
void select448(const float* __restrict__ rois,    // [B, kN, 4]
               const float* __restrict__ scores)  // [B, kN]
{
    const int b    = blockIdx.x;
    const int tid  = threadIdx.x;
    const int lane = tid & 63;
    const int wave = tid >> 6;

    __shared__ float                  s_score[kN];          // 8 KB
    __shared__ __align__(16) unsigned s_hist[kNB];          // 32 KB -> cnt_gt
    __shared__ int                    s_bhead[kNB];         // 32 KB list heads
    __shared__ int                    s_wtot[16];
    __shared__ unsigned long long     s_candKey[kCandMax];  // 8 KB
    __shared__ int                    s_candIdx[kCandMax];  // 4 KB
    __shared__ int                    s_candNext[kCandMax]; // 4 KB
    __shared__ int                    s_candCount;

    const float4* rois4 = reinterpret_cast<const float4*>(rois) + (size_t)b * kN;
    const float*  bsc   = scores + (size_t)b * kN;

    if (tid == 0) g_done[b] = 0;                 // handshake reset (pre-mask)
    for (int i = tid; i < kNB; i += kT) { s_hist[i] = 0u; s_bhead[i] = -1; }
    if (tid == 0) s_candCount = 0;
    __syncthreads();

    // A: load + histogram (13-bit key prefix)
    for (int i = tid; i < kN; i += kT) {
        const float s = bsc[i];
        s_score[i] = s;
        atomicAdd(&s_hist[scoreKey(s) >> 19], 1u);
    }
    __syncthreads();

    // B: cnt_gt per bucket (elements in strictly-higher buckets)
    {
        const int q0 = tid * 8;
        const uint4 hA = *reinterpret_cast<const uint4*>(&s_hist[q0]);
        const uint4 hB = *reinterpret_cast<const uint4*>(&s_hist[q0 + 4]);
        int p = (int)(hA.x + hA.y + hA.z + hA.w + hB.x + hB.y + hB.z + hB.w);
        for (int d = 1; d < 64; d <<= 1) {
            const int x = __shfl_up(p, d);
            if (lane >= d) p += x;
        }
        const int wtot = __shfl(p, 63);
        if (lane == 63) s_wtot[wave] = wtot;
        __syncthreads();
        int above = wtot - p;
        for (int w2 = wave + 1; w2 < 16; ++w2) above += s_wtot[w2];
        const unsigned c7 = (unsigned)above;
        const unsigned c6 = c7 + hB.w;
        const unsigned c5 = c6 + hB.z;
        const unsigned c4 = c5 + hB.y;
        const unsigned c3 = c4 + hB.x;
        const unsigned c2 = c3 + hA.w;
        const unsigned c1 = c2 + hA.z;
        const unsigned c0 = c1 + hA.y;
        __syncthreads();
        *reinterpret_cast<uint4*>(&s_hist[q0])     = make_uint4(c0, c1, c2, c3);
        *reinterpret_cast<uint4*>(&s_hist[q0 + 4]) = make_uint4(c4, c5, c6, c7);
        __syncthreads();
    }

    // C1: candidate selection — ballot-aggregated alloc
    for (int i = tid; i < kN; i += kT) {            // kN/kT = 2 uniform iters
        const unsigned key = scoreKey(s_score[i]);
        const unsigned bk  = key >> 19;
        const bool isCand  = s_hist[bk] < (unsigned)kM;
        const unsigned long long wm = __ballot(isCand);
        int base = 0;
        if (lane == 0 && wm)
            base = atomicAdd(&s_candCount, (int)__popcll(wm));
        base = __shfl(base, 0);
        if (isCand) {
            const int pos = base + (int)__popcll(wm & ((1ull << lane) - 1ull));
            if (pos < kCandMax) {
                s_candIdx[pos]  = i;
                s_candKey[pos]  = ((unsigned long long)key << 32) |
                                  (unsigned)(~(unsigned)i);
                s_candNext[pos] = atomicExch(&s_bhead[bk], pos);
            }
        }
    }
    __syncthreads();
    const int m = s_candCount;

    if (m <= kCandMax) {
        // C2: rank = cnt_gt[bucket] + within-bucket greater-count (list walk)
        for (int t = tid; t < m; t += kT) {
            const unsigned long long myK = s_candKey[t];
            const unsigned bk = (unsigned)(myK >> 51);   // top 13 bits of key
            int rank = (int)s_hist[bk];                  // cnt_gt
            int p = s_bhead[bk];
            while (p != -1) {
                rank += (s_candKey[p] > myK);
                p = s_candNext[p];
            }
            if (rank < kM) {
                const int i = s_candIdx[t];
                g_order[b][rank] = i;
                g_boxes[b][rank] = canonBox(rois4[i]);
            }
        }
    } else {
        for (int i = tid; i < kN; i += kT) {        // overflow: exact full rank
            const float si = s_score[i];
            int rank = 0;
            for (int j = 0; j < kN; ++j) {
                const float sj = s_score[j];
                rank += (sj > si) || (sj == si && j < i);
            }
            if (rank < kM) {
                g_order[b][rank] = i;
                g_boxes[b][rank] = canonBox(rois4[i]);
            }
        }
    }
}

// -------------------------------------------------- K2: mask + last-block scan
__global__ __launch_bounds__(kT)
void maskscan_p(const float* __restrict__ rois,     // [B, kN, 4] orig
                const float* __restrict__ scores,   // [B, kN] (insurance only)
                float* __restrict__ out,            // [B, max_out, 4]
                int max_out)
{
    const int cc   = blockIdx.x;                  // chunk 0..kNCH-1
    const int b    = blockIdx.y;
    const int tid  = threadIdx.x;
    const int lane = tid & 63;
    const int wave = tid >> 6;

    __shared__ float4 s_box[kM];                  // mask phase
    __shared__ float  s_area[kM];
    __shared__ int    s_islast;
    // scan/insurance phase (only the winning block touches these)
    __shared__ int    s_keep[512];
    __shared__ int    s_count, s_eran;
    __shared__ int    s_ford[kN];
    __shared__ float  s_score[kN];
    __shared__ float4 s_kbox[512];
    __shared__ float  s_karea[512];

    // ---- mask phase (R13/R20-proven) ----
    const int nrows = (cc + 1) * 64;
    for (int t = tid; t < nrows; t += kT) {
        const float4 c = g_boxes[b][t];
        s_box[t]  = c;
        s_area[t] = (c.z - c.x) * (c.w - c.y);
    }
    __syncthreads();

    const int ntask = (cc + 1) * 4;               // (kblock, rowgroup) tasks
    for (int tsk = wave; tsk < ntask; tsk += 16) {
        const int k  = tsk >> 2;
        const int rg = tsk & 3;
        const float4 bj = s_box[k * 64 + lane];   // hoisted per task
        const float  aj = s_area[k * 64 + lane];
        const int rbase = cc * 64 + rg * 16;
        for (int rr = 0; rr < 16; ++rr) {
            const int    row = rbase + rr;
            const float4 bi  = s_box[row];        // broadcast
            const float iy1 = fmaxf(bi.x, bj.x);
            const float ix1 = fmaxf(bi.y, bj.y);
            const float iy2 = fminf(bi.z, bj.z);
            const float ix2 = fminf(bi.w, bj.w);
            const float inter = fmaxf(iy2 - iy1, 0.0f) * fmaxf(ix2 - ix1, 0.0f);
            const float uni   = s_area[row] + aj - inter;
            const bool  sup   = (uni > 0.0f) && (inter / uni > kIouThr);
            const unsigned long long bal = __ballot(sup);  // bit l <-> k*64+l
            if ((lane >> 1) == k)                 // lanes 2k, 2k+1 write
                g_mask[b][row][lane] =
                    (lane & 1) ? (unsigned)(bal >> 32) : (unsigned)bal;
        }
    }

    // ---- handshake: release writes, 7th finisher per batch continues ----
    __threadfence();                              // each thread: writes visible
    __syncthreads();                              // all threads fenced
    if (tid == 0)
        s_islast = (atomicAdd(&g_done[b], 1) == kNCH - 1);
    __syncthreads();
    if (!s_islast) return;
    __threadfence();                              // acquire side

    // ---- scan (R19-proven wave-0 body, reads g_mask globally) ----
    if (wave == 0) {
        int  count   = 0;
        bool stopped = false;
        unsigned kw0=0,kw1=0,kw2=0,kw3=0,kw4=0,kw5=0,kw6=0,
                 kw7=0,kw8=0,kw9=0,kw10=0,kw11=0,kw12=0,kw13=0;
        const unsigned long long lowm = (1ull << lane) - 1ull;

#define DECLROW(P0,P1,P2,P3, CH)                                              \
    uint4 P0, P1, P2, P3;                                                     \
    {                                                                         \
        const uint4* rp_ = reinterpret_cast<const uint4*>(                    \
            &g_mask[b][(CH) * 64 + lane][0]);                                 \
        P0 = rp_[0]; P1 = rp_[1]; P2 = rp_[2]; P3 = rp_[3];                   \
    }
        DECLROW(a0,a1,a2,a3, 0)
        DECLROW(b0,b1,b2,b3, 1)
        DECLROW(c0,c1,c2,c3, 2)
        DECLROW(d0,d1,d2,d3, 3)
        DECLROW(e0,e1,e2,e3, 4)
        DECLROW(f0,f1,f2,f3, 5)
        DECLROW(g0,g1,g2,g3, 6)
#undef DECLROW

#define CHUNK(B0,B1,B2,B3, DW, LO, HI, KWLO, KWHI, CH)                        \
    if (!stopped) {                                                           \
        const unsigned acc_ =                                                 \
            (B0.x & kw0)  | (B0.y & kw1)  | (B0.z & kw2)  | (B0.w & kw3)  |   \
            (B1.x & kw4)  | (B1.y & kw5)  | (B1.z & kw6)  | (B1.w & kw7)  |   \
            (B2.x & kw8)  | (B2.y & kw9)  | (B2.z & kw10) | (B2.w & kw11) |   \
            (B3.x & kw12) | (B3.y & kw13);                                    \
        const unsigned long long prev64_ = __ballot(acc_ != 0u);              \
        const unsigned long long alive0_ = ~prev64_;                          \
        const unsigned long long mycol_  =                                    \
            ((unsigned long long)(DW.HI) << 32) | (unsigned long long)(DW.LO);\
        const bool dirtyl_ = ((alive0_ >> lane) & 1ull) &&                    \
                             ((mycol_ & lowm & alive0_) != 0ull);             \
        const unsigned long long dirtyB_ = __ballot(dirtyl_);                 \
        unsigned long long kept_ = alive0_ & ~dirtyB_;   /* clean => kept */  \
        unsigned long long dl_ = dirtyB_;                                     \
        while (dl_) {                              /* ~2-3 iters on bench */  \
            const int l_ = __builtin_ctzll(dl_);                              \
            dl_ &= dl_ - 1ull;                                                \
            const unsigned sLo_ = (unsigned)__builtin_amdgcn_readlane((int)(DW.LO), l_); \
            const unsigned sHi_ = (unsigned)__builtin_amdgcn_readlane((int)(DW.HI), l_); \
            const unsigned long long col_ =                                   \
                ((unsigned long long)sHi_ << 32) | sLo_;                      \
            const unsigned long long lml_ = (1ull << l_) - 1ull;              \
            if ((col_ & kept_ & lml_) == 0ull) kept_ |= (1ull << l_);         \
        }                                                                     \
        const int count0_ = count;                                            \
        count = count0_ + (int)__popcll(kept_);                               \
        if ((kept_ >> lane) & 1ull)                                           \
            s_keep[count0_ + (int)__popcll(kept_ & lowm)] = (CH) * 64 + lane; \
        if (count >= max_out) stopped = true;                                 \
        KWLO = (unsigned)kept_;                                               \
        KWHI = (unsigned)(kept_ >> 32);                                       \
    }
        CHUNK(a0,a1,a2,a3, a0, x, y, kw0,  kw1,  0)
        CHUNK(b0,b1,b2,b3, b0, z, w, kw2,  kw3,  1)
        CHUNK(c0,c1,c2,c3, c1, x, y, kw4,  kw5,  2)
        CHUNK(d0,d1,d2,d3, d1, z, w, kw6,  kw7,  3)
        CHUNK(e0,e1,e2,e3, e2, x, y, kw8,  kw9,  4)
        CHUNK(f0,f1,f2,f3, f2, z, w, kw10, kw11, 5)
        CHUNK(g0,g1,g2,g3, g3, x, y, kw12, kw13, 6)
#undef CHUNK
        if (lane == 0) { s_count = count; s_eran = 0; }
    }
    __syncthreads();

    const float4* rois4 = reinterpret_cast<const float4*>(rois) + (size_t)b * kN;

    // ---- block-wide exact insurance continuation (R17-proven; never taken
    //      on bench data) ----
    if (s_count < max_out) {
        if (tid == 0) s_eran = 1;
        const float* bsc = scores + (size_t)b * kN;
        for (int i = tid; i < kN; i += kT) s_score[i] = bsc[i];
        __syncthreads();
        for (int i = tid; i < kN; i += kT) {         // full stable rank
            const float si = s_score[i];
            int rank = 0;
            for (int j = 0; j < kN; ++j) {
                const float sj = s_score[j];
                rank += (sj > si) || (sj == si && j < i);
            }
            s_ford[rank] = i;
        }
        __syncthreads();
        int count = s_count;
        for (int k2 = tid; k2 < count; k2 += kT) {   // kept-list canon boxes
            const float4 c = g_boxes[b][s_keep[k2]];
            s_kbox[k2]  = c;
            s_karea[k2] = (c.z - c.x) * (c.w - c.y);
        }
        __syncthreads();
        for (int p = kM; p < kN && count < max_out; ++p) {
            const int    oi = s_ford[p];
            const float4 bi = canonBox(rois4[oi]);
            const float  ai = (bi.z - bi.x) * (bi.w - bi.y);
            bool supb = false;
            for (int k2 = lane; k2 < count; k2 += 64) {  // identical per wave
                const float4 bk = s_kbox[k2];
                const float iy1 = fmaxf(bi.x, bk.x);
                const float ix1 = fmaxf(bi.y, bk.y);
                const float iy2 = fminf(bi.z, bk.z);
                const float ix2 = fminf(bi.w, bk.w);
                const float inter = fmaxf(iy2 - iy1, 0.0f) * fmaxf(ix2 - ix1, 0.0f);
                const float uni   = s_karea[k2] + ai - inter;  // f32 add commutes
                supb = supb || ((uni > 0.0f) && (inter / uni > kIouThr));
            }
            if (!__any(supb)) {
                if (tid == 0) {
                    s_keep[count]  = p;              // sorted position
                    s_kbox[count]  = bi;
                    s_karea[count] = ai;
                }
                ++count;
            }
            __syncthreads();
        }
        if (tid == 0) s_count = count;
        __syncthreads();
    }

    // ---- output (pad with original box 0, like the reference) ----
    const int cnt  = s_count;
    const int eran = s_eran;
    float4* out4 = reinterpret_cast<float4*>(out) + (size_t)b * max_out;
    for (int c2 = tid; c2 < max_out; c2 += kT) {
        int oidx = 0;
        if (c2 < cnt) {
            const int pos = s_keep[c2];
            oidx = (pos < kM) ? g_order[b][pos] : (eran ? s_ford[pos] : 0);
        }
        out4[c2] = rois4[oidx];
    }
}

// ------------------------------------------------- fallback (round-1 kernel)
constexpr int kFbThreads = 1024;

__global__ __launch_bounds__(kFbThreads)
void nms_fallback(const float* __restrict__ rois, const float* __restrict__ scores,
                  float* __restrict__ out, int max_out)
{
    const int b   = blockIdx.x;
    const int tid = threadIdx.x;
    __shared__ float        s_score[kN];
    __shared__ int          s_order[kN];
    __shared__ float4       s_box[kN];
    __shared__ float        s_area[kN];
    __shared__ unsigned int s_sup[kN / 32];
    __shared__ int          s_count;
    const float* brois   = rois   + (size_t)b * kN * 4;
    const float* bscores = scores + (size_t)b * kN;
    for (int i = tid; i < kN; i += kFbThreads) s_score[i] = bscores[i];
    for (int i = tid; i < kN / 32; i += kFbThreads) s_sup[i] = 0u;
    if (tid == 0) s_count = 0;
    __syncthreads();
    for (int i = tid; i < kN; i += kFbThreads) {
        const float si = s_score[i];
        int rank = 0;
        const float4* s4 = reinterpret_cast<const float4*>(s_score);
        for (int j4 = 0; j4 < kN / 4; ++j4) {
            const float4 v = s4[j4];
            const int j = j4 * 4;
            rank += (v.x > si) || (v.x == si && (j + 0) < i);
            rank += (v.y > si) || (v.y == si && (j + 1) < i);
            rank += (v.z > si) || (v.z == si && (j + 2) < i);
            rank += (v.w > si) || (v.w == si && (j + 3) < i);
        }
        s_order[rank] = i;
    }
    __syncthreads();
    for (int r = tid; r < kN; r += kFbThreads) {
        const int idx = s_order[r];
        const float4 bx = *reinterpret_cast<const float4*>(brois + (size_t)idx * 4);
        const float cy1 = fminf(bx.x, bx.z), cy2 = fmaxf(bx.x, bx.z);
        const float cx1 = fminf(bx.y, bx.w), cx2 = fmaxf(bx.y, bx.w);
        s_box[r]  = make_float4(cy1, cx1, cy2, cx2);
        s_area[r] = (cy2 - cy1) * (cx2 - cx1);
    }
    __syncthreads();
    for (int i = 0; i < kN; ++i) {
        const bool sup_i = (s_sup[i >> 5] >> (i & 31)) & 1u;
        if (!sup_i) {
            const float4 bi = s_box[i];
            const float  ai = s_area[i];
            for (int j = i + 1 + tid; j < kN; j += kFbThreads) {
                const float4 bj = s_box[j];
                const float iy1 = fmaxf(bi.x, bj.x);
                const float ix1 = fmaxf(bi.y, bj.y);
                const float iy2 = fminf(bi.z, bj.z);
                const float ix2 = fminf(bi.w, bj.w);
                const float inter = fmaxf(iy2 - iy1, 0.0f) * fmaxf(ix2 - ix1, 0.0f);
                const float uni   = ai + s_area[j] - inter;
                const float iou   = (uni > 0.0f) ? (inter / uni) : 0.0f;
                if (iou > kIouThr) atomicOr(&s_sup[j >> 5], 1u << (j & 31));
            }
            if (tid == 0) {
                const int c = s_count;
                if (c < max_out) {
                    const int oidx = s_order[i];
                    reinterpret_cast<float4*>(out)[(size_t)b * max_out + c] =
                        *reinterpret_cast<const float4*>(brois + (size_t)oidx * 4);
                }
                s_count = c + 1;
            }
        }
        __syncthreads();
        const bool stop = (s_count >= max_out);
        __syncthreads();
        if (stop) break;
    }
    const int c = min(s_count, max_out);
    const float4 pad = *reinterpret_cast<const float4*>(brois);
    for (int r = c + tid; r < max_out; r += kFbThreads) {
        reinterpret_cast<float4*>(out)[(size_t)b * max_out + r] = pad;
    }
}

// ---------------------------------------------------------------- launch
extern "C" void kernel_launch(void* const* d_in, const int* in_sizes, int n_in,
                              void* d_out, int out_size, void* d_ws, size_t ws_size,
                              hipStream_t stream)
{
    const float* rois   = (const float*)d_in[0];
    const float* scores = (const float*)d_in[1];
    float* out = (float*)d_out;

    const int B       = in_sizes[1] / kN;        // scores are [B, kN]
    const int max_out = out_size / (4 * B);      // out is [B, max_out, 4]

    if (B <= kB && max_out <= 512) {
        select448<<<dim3(B), dim3(kT), 0, stream>>>(rois, scores);
        maskscan_p<<<dim3(kNCH, B), dim3(kT), 0, stream>>>(rois, scores, out, max_out);
    } else {
        nms_fallback<<<dim3(B), dim3(kFbThreads), 0, stream>>>(rois, scores, out, max_out);
    }
}

// Round 22
// 26.893 us; speedup vs baseline: 2.8404x; 2.8404x over previous
//
#include <hip/hip_runtime.h>

// 3-kernel windowed NMS (bit-exact vs the JAX reference). FINAL: this is the
// best-measured configuration (R20, 26.96us; 14.6x over the R1 baseline).
// R21's last-block-done merge regressed 2.8x (device-scope fences pushed the
// L2-resident mask to HBM) and is reverted. Residual time is per-dispatch
// fixed cost + low-clock latency-bound phase work; HBM 0.1%, VALU ~4%.
//  K1 select448: A 8192-bucket histogram + B cnt_gt + C bucket-list rank
//                -> g_boxes/g_order for ranks < kM.
//  K2 mask448p : grid (chunk, batch): windowed suppression bit-rows -> g_mask.
//  K3 scan448g : 1 wave/batch: upfront-loaded clean/dirty greedy resolve;
//                insurance continuation; output.
// Fallback single kernel (R1-proven) outside the fast path.

constexpr int   kN       = 2048;
constexpr int   kB       = 16;        // max batches in fast path
constexpr int   kM       = 448;       // sorted window (multiple of 64)
constexpr int   kNCH     = kM / 64;   // 7 chunks
constexpr int   kMW      = kM / 32;   // 14 mask words per row
constexpr int   kNB      = 8192;      // score buckets
constexpr int   kCandMax = 1024;
constexpr int   kT       = 1024;      // 16 waves
constexpr float kIouThr  = 0.7f;

__device__ __align__(16) float4   g_boxes[kB][kM];     // canonical, rank order
__device__            int         g_order[kB][kM];     // original idx by rank
__device__ __align__(16) unsigned g_mask[kB][kM][16];  // 64B rows (words 0..13)

__device__ __forceinline__ unsigned scoreKey(float s) {
    const unsigned b = __float_as_uint(s);
    if (s == 0.0f) return 0x80000000u;
    return (b & 0x80000000u) ? ~b : (b | 0x80000000u);
}

__device__ __forceinline__ float4 canonBox(const float4 bx) {
    const float cy1 = fminf(bx.x, bx.z), cy2 = fmaxf(bx.x, bx.z);
    const float cx1 = fminf(bx.y, bx.w), cx2 = fmaxf(bx.y, bx.w);
    return make_float4(cy1, cx1, cy2, cx2);
}

// ---------------------------------------------------------------- K1: select
__global__ __launch_bounds__(kT, 1)
void select448(const float* __restrict__ rois,    // [B, kN, 4]
               const float* __restrict__ scores)  // [B, kN]
{
    const int b    = blockIdx.x;
    const int tid  = threadIdx.x;
    const int lane = tid & 63;
    const int wave = tid >> 6;

    __shared__ float                  s_score[kN];          // 8 KB
    __shared__ __align__(16) unsigned s_hist[kNB];          // 32 KB -> cnt_gt
    __shared__ int                    s_bhead[kNB];         // 32 KB list heads
    __shared__ int                    s_wtot[16];
    __shared__ unsigned long long     s_candKey[kCandMax];  // 8 KB
    __shared__ int                    s_candIdx[kCandMax];  // 4 KB
    __shared__ int                    s_candNext[kCandMax]; // 4 KB
    __shared__ int                    s_candCount;

    const float4* rois4 = reinterpret_cast<const float4*>(rois) + (size_t)b * kN;
    const float*  bsc   = scores + (size_t)b * kN;

    for (int i = tid; i < kNB; i += kT) { s_hist[i] = 0u; s_bhead[i] = -1; }
    if (tid == 0) s_candCount = 0;
    __syncthreads();

    // A: load + histogram (13-bit key prefix)
    for (int i = tid; i < kN; i += kT) {
        const float s = bsc[i];
        s_score[i] = s;
        atomicAdd(&s_hist[scoreKey(s) >> 19], 1u);
    }
    __syncthreads();

    // B: cnt_gt per bucket (elements in strictly-higher buckets)
    {
        const int q0 = tid * 8;
        const uint4 hA = *reinterpret_cast<const uint4*>(&s_hist[q0]);
        const uint4 hB = *reinterpret_cast<const uint4*>(&s_hist[q0 + 4]);
        int p = (int)(hA.x + hA.y + hA.z + hA.w + hB.x + hB.y + hB.z + hB.w);
        for (int d = 1; d < 64; d <<= 1) {
            const int x = __shfl_up(p, d);
            if (lane >= d) p += x;
        }
        const int wtot = __shfl(p, 63);
        if (lane == 63) s_wtot[wave] = wtot;
        __syncthreads();
        int above = wtot - p;
        for (int w2 = wave + 1; w2 < 16; ++w2) above += s_wtot[w2];
        const unsigned c7 = (unsigned)above;
        const unsigned c6 = c7 + hB.w;
        const unsigned c5 = c6 + hB.z;
        const unsigned c4 = c5 + hB.y;
        const unsigned c3 = c4 + hB.x;
        const unsigned c2 = c3 + hA.w;
        const unsigned c1 = c2 + hA.z;
        const unsigned c0 = c1 + hA.y;
        __syncthreads();
        *reinterpret_cast<uint4*>(&s_hist[q0])     = make_uint4(c0, c1, c2, c3);
        *reinterpret_cast<uint4*>(&s_hist[q0 + 4]) = make_uint4(c4, c5, c6, c7);
        __syncthreads();
    }

    // C1: candidate selection — ballot-aggregated alloc
    for (int i = tid; i < kN; i += kT) {            // kN/kT = 2 uniform iters
        const unsigned key = scoreKey(s_score[i]);
        const unsigned bk  = key >> 19;
        const bool isCand  = s_hist[bk] < (unsigned)kM;
        const unsigned long long wm = __ballot(isCand);
        int base = 0;
        if (lane == 0 && wm)
            base = atomicAdd(&s_candCount, (int)__popcll(wm));
        base = __shfl(base, 0);
        if (isCand) {
            const int pos = base + (int)__popcll(wm & ((1ull << lane) - 1ull));
            if (pos < kCandMax) {
                s_candIdx[pos]  = i;
                s_candKey[pos]  = ((unsigned long long)key << 32) |
                                  (unsigned)(~(unsigned)i);
                s_candNext[pos] = atomicExch(&s_bhead[bk], pos);
            }
        }
    }
    __syncthreads();
    const int m = s_candCount;

    if (m <= kCandMax) {
        // C2: rank = cnt_gt[bucket] + within-bucket greater-count (list walk)
        for (int t = tid; t < m; t += kT) {
            const unsigned long long myK = s_candKey[t];
            const unsigned bk = (unsigned)(myK >> 51);   // top 13 bits of key
            int rank = (int)s_hist[bk];                  // cnt_gt
            int p = s_bhead[bk];
            while (p != -1) {
                rank += (s_candKey[p] > myK);
                p = s_candNext[p];
            }
            if (rank < kM) {
                const int i = s_candIdx[t];
                g_order[b][rank] = i;
                g_boxes[b][rank] = canonBox(rois4[i]);
            }
        }
    } else {
        for (int i = tid; i < kN; i += kT) {        // overflow: exact full rank
            const float si = s_score[i];
            int rank = 0;
            for (int j = 0; j < kN; ++j) {
                const float sj = s_score[j];
                rank += (sj > si) || (sj == si && j < i);
            }
            if (rank < kM) {
                g_order[b][rank] = i;
                g_boxes[b][rank] = canonBox(rois4[i]);
            }
        }
    }
}

// -------------------------------------------------------------- K2: mask
__global__ __launch_bounds__(kT)
void mask448p()
{
    const int cc = blockIdx.x;                    // chunk 0..kNCH-1
    const int b  = blockIdx.y;
    const int tid  = threadIdx.x;
    const int lane = tid & 63;
    const int wave = tid >> 6;

    __shared__ float4 s_box[kM];
    __shared__ float  s_area[kM];
    const int nrows = (cc + 1) * 64;
    for (int t = tid; t < nrows; t += kT) {
        const float4 c = g_boxes[b][t];
        s_box[t]  = c;
        s_area[t] = (c.z - c.x) * (c.w - c.y);
    }
    __syncthreads();

    const int ntask = (cc + 1) * 4;               // (kblock, rowgroup) tasks
    for (int tsk = wave; tsk < ntask; tsk += 16) {
        const int k  = tsk >> 2;
        const int rg = tsk & 3;
        const float4 bj = s_box[k * 64 + lane];   // hoisted per task
        const float  aj = s_area[k * 64 + lane];
        const int rbase = cc * 64 + rg * 16;
        for (int rr = 0; rr < 16; ++rr) {
            const int    row = rbase + rr;
            const float4 bi  = s_box[row];        // broadcast
            const float iy1 = fmaxf(bi.x, bj.x);
            const float ix1 = fmaxf(bi.y, bj.y);
            const float iy2 = fminf(bi.z, bj.z);
            const float ix2 = fminf(bi.w, bj.w);
            const float inter = fmaxf(iy2 - iy1, 0.0f) * fmaxf(ix2 - ix1, 0.0f);
            const float uni   = s_area[row] + aj - inter;
            const bool  sup   = (uni > 0.0f) && (inter / uni > kIouThr);
            const unsigned long long bal = __ballot(sup);  // bit l <-> k*64+l
            if ((lane >> 1) == k)                 // lanes 2k, 2k+1 write
                g_mask[b][row][lane] =
                    (lane & 1) ? (unsigned)(bal >> 32) : (unsigned)bal;
        }
    }
}

// -------------------------------------------------------------- K3: scan
__global__ __launch_bounds__(64)
void scan448g(const float* __restrict__ rois,     // [B, kN, 4] orig
              const float* __restrict__ scores,   // [B, kN] (insurance only)
              float* __restrict__ out,            // [B, max_out, 4]
              int max_out)
{
    const int b    = blockIdx.x;
    const int lane = threadIdx.x;

    __shared__ int    s_keep[512];     // kept SORTED positions
    __shared__ int    s_ford[kN];      // insurance: full order
    __shared__ float  s_score[kN];     // insurance
    __shared__ float4 s_kbox[512];     // insurance
    __shared__ float  s_karea[512];

    int  count   = 0;
    bool stopped = false;

    // kept-bitmap over sorted positions: 14 uniform scalars
    unsigned kw0=0,kw1=0,kw2=0,kw3=0,kw4=0,kw5=0,kw6=0,
             kw7=0,kw8=0,kw9=0,kw10=0,kw11=0,kw12=0,kw13=0;

    const unsigned long long lowm = (1ull << lane) - 1ull;  // rows before lane

    // ALL 7 chunks' row words loaded upfront (28 uint4 / lane) — mask is
    // decision-independent, one memory round-trip.
#define DECLROW(P0,P1,P2,P3, CH)                                              \
    uint4 P0, P1, P2, P3;                                                     \
    {                                                                         \
        const uint4* rp_ = reinterpret_cast<const uint4*>(                    \
            &g_mask[b][(CH) * 64 + lane][0]);                                 \
        P0 = rp_[0]; P1 = rp_[1]; P2 = rp_[2]; P3 = rp_[3];                   \
    }

    DECLROW(a0,a1,a2,a3, 0)
    DECLROW(b0,b1,b2,b3, 1)
    DECLROW(c0,c1,c2,c3, 2)
    DECLROW(d0,d1,d2,d3, 3)
    DECLROW(e0,e1,e2,e3, 4)
    DECLROW(f0,f1,f2,f3, 5)
    DECLROW(g0,g1,g2,g3, 6)
#undef DECLROW

    // Resolve chunk CH from B0..B3 via clean/dirty (R14-proven).
    // DW.LO/DW.HI = diag words 2CH,2CH+1 (lane's own column bits).
#define CHUNK(B0,B1,B2,B3, DW, LO, HI, KWLO, KWHI, CH)                        \
    if (!stopped) {                                                           \
        const unsigned acc_ =                                                 \
            (B0.x & kw0)  | (B0.y & kw1)  | (B0.z & kw2)  | (B0.w & kw3)  |   \
            (B1.x & kw4)  | (B1.y & kw5)  | (B1.z & kw6)  | (B1.w & kw7)  |   \
            (B2.x & kw8)  | (B2.y & kw9)  | (B2.z & kw10) | (B2.w & kw11) |   \
            (B3.x & kw12) | (B3.y & kw13);                                    \
        const unsigned long long prev64_ = __ballot(acc_ != 0u);              \
        const unsigned long long alive0_ = ~prev64_;                          \
        const unsigned long long mycol_  =                                    \
            ((unsigned long long)(DW.HI) << 32) | (unsigned long long)(DW.LO);\
        const bool dirtyl_ = ((alive0_ >> lane) & 1ull) &&                    \
                             ((mycol_ & lowm & alive0_) != 0ull);             \
        const unsigned long long dirtyB_ = __ballot(dirtyl_);                 \
        unsigned long long kept_ = alive0_ & ~dirtyB_;   /* clean => kept */  \
        unsigned long long dl_ = dirtyB_;                                     \
        while (dl_) {                              /* ~2-3 iters on bench */  \
            const int l_ = __builtin_ctzll(dl_);                              \
            dl_ &= dl_ - 1ull;                                                \
            const unsigned sLo_ = (unsigned)__builtin_amdgcn_readlane((int)(DW.LO), l_); \
            const unsigned sHi_ = (unsigned)__builtin_amdgcn_readlane((int)(DW.HI), l_); \
            const unsigned long long col_ =                                   \
                ((unsigned long long)sHi_ << 32) | sLo_;                      \
            const unsigned long long lml_ = (1ull << l_) - 1ull;              \
            if ((col_ & kept_ & lml_) == 0ull) kept_ |= (1ull << l_);         \
        }                                                                     \
        const int count0_ = count;                                            \
        count = count0_ + (int)__popcll(kept_);                               \
        if ((kept_ >> lane) & 1ull)                                           \
            s_keep[count0_ + (int)__popcll(kept_ & lowm)] = (CH) * 64 + lane; \
        if (count >= max_out) stopped = true;                                 \
        KWLO = (unsigned)kept_;                                               \
        KWHI = (unsigned)(kept_ >> 32);                                       \
    }

    CHUNK(a0,a1,a2,a3, a0, x, y, kw0,  kw1,  0)
    CHUNK(b0,b1,b2,b3, b0, z, w, kw2,  kw3,  1)
    CHUNK(c0,c1,c2,c3, c1, x, y, kw4,  kw5,  2)
    CHUNK(d0,d1,d2,d3, d1, z, w, kw6,  kw7,  3)
    CHUNK(e0,e1,e2,e3, e2, x, y, kw8,  kw9,  4)
    CHUNK(f0,f1,f2,f3, f2, z, w, kw10, kw11, 5)
    CHUNK(g0,g1,g2,g3, g3, x, y, kw12, kw13, 6)
#undef CHUNK

    const float4* rois4 = reinterpret_cast<const float4*>(rois) + (size_t)b * kN;

    // ---- exact insurance continuation (never taken on bench data) ----
    bool eran = false;
    if (count < max_out) {
        eran = true;
        const float* bsc = scores + (size_t)b * kN;
        for (int i = lane; i < kN; i += 64) s_score[i] = bsc[i];
        __syncthreads();
        for (int i = lane; i < kN; i += 64) {       // full stable rank
            const float si = s_score[i];
            int rank = 0;
            for (int j = 0; j < kN; ++j) {
                const float sj = s_score[j];
                rank += (sj > si) || (sj == si && j < i);
            }
            s_ford[rank] = i;
        }
        __syncthreads();
        for (int k2 = lane; k2 < count; k2 += 64) { // kept-list canon boxes
            const float4 c = g_boxes[b][s_keep[k2]];
            s_kbox[k2]  = c;
            s_karea[k2] = (c.z - c.x) * (c.w - c.y);
        }
        __syncthreads();
        for (int p = kM; p < kN && count < max_out; ++p) {
            const int    oi = s_ford[p];
            const float4 bi = canonBox(rois4[oi]);
            const float  ai = (bi.z - bi.x) * (bi.w - bi.y);
            bool supb = false;
            for (int k2 = lane; k2 < count; k2 += 64) {
                const float4 bk = s_kbox[k2];
                const float iy1 = fmaxf(bi.x, bk.x);
                const float ix1 = fmaxf(bi.y, bk.y);
                const float iy2 = fminf(bi.z, bk.z);
                const float ix2 = fminf(bi.w, bk.w);
                const float inter = fmaxf(iy2 - iy1, 0.0f) * fmaxf(ix2 - ix1, 0.0f);
                const float uni   = s_karea[k2] + ai - inter;  // f32 add commutes
                supb = supb || ((uni > 0.0f) && (inter / uni > kIouThr));
            }
            if (!__any(supb)) {
                if (lane == 0) {
                    s_keep[count]  = p;             // sorted position
                    s_kbox[count]  = bi;
                    s_karea[count] = ai;
                }
                ++count;
            }
        }
    }

    __syncthreads();                                // LDS visibility

    // ---- output (pad with original box 0, like the reference) ----
    float4* out4 = reinterpret_cast<float4*>(out) + (size_t)b * max_out;
    for (int c2 = lane; c2 < max_out; c2 += 64) {
        int oidx = 0;
        if (c2 < count) {
            const int pos = s_keep[c2];
            oidx = (pos < kM) ? g_order[b][pos] : s_ford[pos];
        }
        out4[c2] = rois4[oidx];
    }
    (void)eran;
}

// ------------------------------------------------- fallback (round-1 kernel)
constexpr int kFbThreads = 1024;

__global__ __launch_bounds__(kFbThreads)
void nms_fallback(const float* __restrict__ rois, const float* __restrict__ scores,
                  float* __restrict__ out, int max_out)
{
    const int b   = blockIdx.x;
    const int tid = threadIdx.x;
    __shared__ float        s_score[kN];
    __shared__ int          s_order[kN];
    __shared__ float4       s_box[kN];
    __shared__ float        s_area[kN];
    __shared__ unsigned int s_sup[kN / 32];
    __shared__ int          s_count;
    const float* brois   = rois   + (size_t)b * kN * 4;
    const float* bscores = scores + (size_t)b * kN;
    for (int i = tid; i < kN; i += kFbThreads) s_score[i] = bscores[i];
    for (int i = tid; i < kN / 32; i += kFbThreads) s_sup[i] = 0u;
    if (tid == 0) s_count = 0;
    __syncthreads();
    for (int i = tid; i < kN; i += kFbThreads) {
        const float si = s_score[i];
        int rank = 0;
        const float4* s4 = reinterpret_cast<const float4*>(s_score);
        for (int j4 = 0; j4 < kN / 4; ++j4) {
            const float4 v = s4[j4];
            const int j = j4 * 4;
            rank += (v.x > si) || (v.x == si && (j + 0) < i);
            rank += (v.y > si) || (v.y == si && (j + 1) < i);
            rank += (v.z > si) || (v.z == si && (j + 2) < i);
            rank += (v.w > si) || (v.w == si && (j + 3) < i);
        }
        s_order[rank] = i;
    }
    __syncthreads();
    for (int r = tid; r < kN; r += kFbThreads) {
        const int idx = s_order[r];
        const float4 bx = *reinterpret_cast<const float4*>(brois + (size_t)idx * 4);
        const float cy1 = fminf(bx.x, bx.z), cy2 = fmaxf(bx.x, bx.z);
        const float cx1 = fminf(bx.y, bx.w), cx2 = fmaxf(bx.y, bx.w);
        s_box[r]  = make_float4(cy1, cx1, cy2, cx2);
        s_area[r] = (cy2 - cy1) * (cx2 - cx1);
    }
    __syncthreads();
    for (int i = 0; i < kN; ++i) {
        const bool sup_i = (s_sup[i >> 5] >> (i & 31)) & 1u;
        if (!sup_i) {
            const float4 bi = s_box[i];
            const float  ai = s_area[i];
            for (int j = i + 1 + tid; j < kN; j += kFbThreads) {
                const float4 bj = s_box[j];
                const float iy1 = fmaxf(bi.x, bj.x);
                const float ix1 = fmaxf(bi.y, bj.y);
                const float iy2 = fminf(bi.z, bj.z);
                const float ix2 = fminf(bi.w, bj.w);
                const float inter = fmaxf(iy2 - iy1, 0.0f) * fmaxf(ix2 - ix1, 0.0f);
                const float uni   = ai + s_area[j] - inter;
                const float iou   = (uni > 0.0f) ? (inter / uni) : 0.0f;
                if (iou > kIouThr) atomicOr(&s_sup[j >> 5], 1u << (j & 31));
            }
            if (tid == 0) {
                const int c = s_count;
                if (c < max_out) {
                    const int oidx = s_order[i];
                    reinterpret_cast<float4*>(out)[(size_t)b * max_out + c] =
                        *reinterpret_cast<const float4*>(brois + (size_t)oidx * 4);
                }
                s_count = c + 1;
            }
        }
        __syncthreads();
        const bool stop = (s_count >= max_out);
        __syncthreads();
        if (stop) break;
    }
    const int c = min(s_count, max_out);
    const float4 pad = *reinterpret_cast<const float4*>(brois);
    for (int r = c + tid; r < max_out; r += kFbThreads) {
        reinterpret_cast<float4*>(out)[(size_t)b * max_out + r] = pad;
    }
}

// ---------------------------------------------------------------- launch
extern "C" void kernel_launch(void* const* d_in, const int* in_sizes, int n_in,
                              void* d_out, int out_size, void* d_ws, size_t ws_size,
                              hipStream_t stream)
{
    const float* rois   = (const float*)d_in[0];
    const float* scores = (const float*)d_in[1];
    float* out = (float*)d_out;

    const int B       = in_sizes[1] / kN;        // scores are [B, kN]
    const int max_out = out_size / (4 * B);      // out is [B, max_out, 4]

    if (B <= kB && max_out <= 512) {
        select448<<<dim3(B), dim3(kT), 0, stream>>>(rois, scores);
        mask448p<<<dim3(kNCH, B), dim3(kT), 0, stream>>>();
        scan448g<<<dim3(B), dim3(64), 0, stream>>>(rois, scores, out, max_out);
    } else {
        nms_fallback<<<dim3(B), dim3(kFbThreads), 0, stream>>>(rois, scores, out, max_out);
    }
}